// Round 1
// baseline (405.857 us; speedup 1.0000x reference)
//
#include <hip/hip_runtime.h>

#define EMB_DIM 64
#define DIM2 128
#define FM_K 10
#define AVG_RATING 4.0f

// 4 samples per 64-lane wave: 16 lanes per sample, float4 (16B) per lane per row.
// fm_V / fc_w / sum(V^2) staged in LDS once per block.
__global__ __launch_bounds__(256) void decoder_fm_kernel(
    const int*   __restrict__ user,
    const int*   __restrict__ item,
    const float* __restrict__ user_emb,
    const float* __restrict__ item_emb,
    const float* __restrict__ fc_w,
    const float* __restrict__ fc_b,
    const float* __restrict__ fm_V,
    const float* __restrict__ b_users,
    const float* __restrict__ b_items,
    float*       __restrict__ out,
    int B)
{
    __shared__ __align__(16) float sV[DIM2 * FM_K];  // 5120 B, row-major [128][10]
    __shared__ __align__(16) float sW[DIM2];         // fc_w
    __shared__ __align__(16) float sS[DIM2];         // per-row sum_k V^2

    // one-time block staging (single barrier: sS computed from global, not sV)
    for (int t = threadIdx.x; t < DIM2 * FM_K; t += 256) sV[t] = fm_V[t];
    if (threadIdx.x < DIM2) {
        sW[threadIdx.x] = fc_w[threadIdx.x];
        float acc = 0.f;
#pragma unroll
        for (int k = 0; k < FM_K; ++k) {
            const float v = fm_V[threadIdx.x * FM_K + k];
            acc += v * v;
        }
        sS[threadIdx.x] = acc;
    }
    __syncthreads();

    const int wave = (int)((blockIdx.x * blockDim.x + threadIdx.x) >> 6);
    const int lane = (int)(threadIdx.x & 63);
    const int g    = lane >> 4;          // sample slot within the wave (0..3)
    const int q    = lane & 15;          // lane within the sample group
    const int s    = wave * 4 + g;
    if (s >= B) return;

    const int uidx = user[s];            // broadcast load (same addr across group)
    const int iidx = item[s];

    // coalesced 256B row gathers: 16 lanes x float4
    const float4 x0 = *reinterpret_cast<const float4*>(user_emb + (size_t)uidx * EMB_DIM + q * 4);
    const float4 x1 = *reinterpret_cast<const float4*>(item_emb + (size_t)iidx * EMB_DIM + q * 4);
    const float  bu = b_users[uidx];     // broadcast across group, used by leader
    const float  bi = b_items[iidx];

    const int du = q * 4;                // this lane's 4 user-half rows
    const int di = EMB_DIM + du;         // this lane's 4 item-half rows

    // 16B-aligned LDS vector reads (du*4 bytes = 16q)
    const float4 wu = *reinterpret_cast<const float4*>(&sW[du]);
    const float4 wi = *reinterpret_cast<const float4*>(&sW[di]);
    const float4 su = *reinterpret_cast<const float4*>(&sS[du]);
    const float4 si = *reinterpret_cast<const float4*>(&sS[di]);

    float red[FM_K + 2];                 // xv[0..9], linear, x^2*sumV2
#pragma unroll
    for (int r = 0; r < FM_K + 2; ++r) red[r] = 0.f;

    const float xu[4]  = {x0.x, x0.y, x0.z, x0.w};
    const float xi_[4] = {x1.x, x1.y, x1.z, x1.w};
    const float wua[4] = {wu.x, wu.y, wu.z, wu.w};
    const float wia[4] = {wi.x, wi.y, wi.z, wi.w};
    const float sua[4] = {su.x, su.y, su.z, su.w};
    const float sia[4] = {si.x, si.y, si.z, si.w};

#pragma unroll
    for (int j = 0; j < 4; ++j) {
        const float a = xu[j];
        const float b = xi_[j];
        const float* vu = &sV[(du + j) * FM_K];
        const float* vi = &sV[(di + j) * FM_K];
#pragma unroll
        for (int k = 0; k < FM_K; ++k)
            red[k] += a * vu[k] + b * vi[k];
        red[FM_K]     += a * wua[j] + b * wia[j];
        red[FM_K + 1] += a * a * sua[j] + b * b * sia[j];
    }

    // butterfly over 16 lanes: offsets 8,4,2,1 -> pure ds_swizzle, no ds_bpermute
#pragma unroll
    for (int off = 8; off > 0; off >>= 1) {
#pragma unroll
        for (int r = 0; r < FM_K + 2; ++r)
            red[r] += __shfl_xor(red[r], off, 16);
    }

    if (q == 0) {
        float inter = 0.f;
#pragma unroll
        for (int k = 0; k < FM_K; ++k) inter += red[k] * red[k];
        // 4 leaders per wave store to consecutive addresses (one transaction)
        out[s] = 0.5f * (inter - red[FM_K + 1]) + red[FM_K] + fc_b[0]
               + bu + bi + AVG_RATING;
    }
}

extern "C" void kernel_launch(void* const* d_in, const int* in_sizes, int n_in,
                              void* d_out, int out_size, void* d_ws, size_t ws_size,
                              hipStream_t stream) {
    const int*   user     = (const int*)  d_in[0];
    const int*   item     = (const int*)  d_in[1];
    // d_in[2] = u_out, d_in[3] = i_out : multiplied by 0 in the reference, never read
    const float* user_emb = (const float*)d_in[4];
    const float* item_emb = (const float*)d_in[5];
    const float* fc_w     = (const float*)d_in[6];
    const float* fc_b     = (const float*)d_in[7];
    const float* fm_V     = (const float*)d_in[8];
    const float* b_users  = (const float*)d_in[9];
    const float* b_items  = (const float*)d_in[10];
    float* out = (float*)d_out;

    const int B = in_sizes[0];
    const int waves   = (B + 3) / 4;                  // 4 samples per wave
    const int threads = 256;                          // 4 waves per block
    const int blocks  = (waves * 64 + threads - 1) / threads;
    decoder_fm_kernel<<<blocks, threads, 0, stream>>>(
        user, item, user_emb, item_emb, fc_w, fc_b, fm_V, b_users, b_items, out, B);
}